// Round 2
// baseline (479.699 us; speedup 1.0000x reference)
//
#include <hip/hip_runtime.h>
#include <hip/hip_bf16.h>

using bf16 = __hip_bfloat16;
typedef short bf16x8v  __attribute__((ext_vector_type(8)));
typedef float f32x16v  __attribute__((ext_vector_type(16)));

#define GLD_LDS16(g, l) __builtin_amdgcn_global_load_lds(                      \
    (const __attribute__((address_space(1))) void*)(g),                        \
    (__attribute__((address_space(3))) void*)(l), 16, 0, 0)

__device__ __forceinline__ float bflo(unsigned int u) {
  union { unsigned int i; float f; } c; c.i = u << 16; return c.f;
}
__device__ __forceinline__ float bfhi(unsigned int u) {
  union { unsigned int i; float f; } c; c.i = u & 0xffff0000u; return c.f;
}
__device__ __forceinline__ unsigned int packbf(float a, float b) {
  return (unsigned int)(__hip_bfloat16_raw(__float2bfloat16(a)).x) |
         ((unsigned int)(__hip_bfloat16_raw(__float2bfloat16(b)).x) << 16);
}
__device__ __forceinline__ unsigned short bfraw(float a) {
  return __hip_bfloat16_raw(__float2bfloat16(a)).x;
}

// ------------------------------------------------- all fp32->bf16 casts, one launch
__global__ void f2b4_all(const float* __restrict__ x,  const float* __restrict__ wk,
                         const float* __restrict__ wv, const float* __restrict__ wr,
                         const float* __restrict__ wo,
                         bf16* __restrict__ x_bf, bf16* __restrict__ wcat,
                         bf16* __restrict__ wo_bf) {
  int i = blockIdx.x * blockDim.x + threadIdx.x;
  const float* s; bf16* d; int idx;
  if (i < 6291456) { s = x; d = x_bf; idx = i; }
  else {
    int j = i - 6291456;
    int seg = j / 147456;
    idx = j - seg * 147456;
    if (seg == 0)      { s = wk; d = wcat; }
    else if (seg == 1) { s = wv; d = wcat + 589824; }
    else if (seg == 2) { s = wr; d = wcat + 1179648; }
    else               { s = wo; d = wo_bf; }
  }
  const float4 f = reinterpret_cast<const float4*>(s)[idx];
  struct B4 { bf16 a, b, c, d; };
  B4 o = { __float2bfloat16(f.x), __float2bfloat16(f.y),
           __float2bfloat16(f.z), __float2bfloat16(f.w) };
  reinterpret_cast<B4*>(d)[idx] = o;
}

// --------------------------------------------------------------- GEMM core
// PROVEN structure (round-0, 161.9us kvr): 128x128 tile, BK=64,
// v_mfma_f32_32x32x16_bf16, swapped operands -> packed epilogue, granule-XOR
// LDS swizzle, global_load_lds width=16, 2-barrier K-loop. 8-phase 256^2
// variant REGRESSED at this shape (K=768 short, 1 block/CU, 4.5-round tail)
// - do not re-apply without fixing those.
__device__ __forceinline__ void gemm_tile_acc(
    const bf16* __restrict__ A, const bf16* __restrict__ W,
    bf16* lds_a, bf16* lds_b, int tid, size_t m0, int n0, f32x16v acc[2][2])
{
  const int lane = tid & 63;
  const int wave = tid >> 6;
  const int l31  = lane & 31;
  const int hi   = lane >> 5;
  const int wr   = (wave >> 1) * 64;
  const int wc   = (wave & 1) * 64;

  int srow[4], scol[4];
#pragma unroll
  for (int q = 0; q < 4; ++q) {
    const int s = tid + q * 256;
    srow[q] = s >> 3;
    scol[q] = (((s & 7) ^ (srow[q] & 7)) * 8);
  }

#pragma unroll
  for (int i = 0; i < 2; ++i)
#pragma unroll
    for (int j = 0; j < 2; ++j)
#pragma unroll
      for (int r = 0; r < 16; ++r) acc[i][j][r] = 0.0f;

  for (int k0 = 0; k0 < 768; k0 += 64) {
    __syncthreads();
#pragma unroll
    for (int q = 0; q < 4; ++q)
      GLD_LDS16(A + (m0 + srow[q]) * 768 + k0 + scol[q], &lds_a[(size_t)(tid + q * 256) * 8]);
#pragma unroll
    for (int q = 0; q < 4; ++q)
      GLD_LDS16(W + (size_t)(n0 + srow[q]) * 768 + k0 + scol[q], &lds_b[(size_t)(tid + q * 256) * 8]);
    __syncthreads();

#pragma unroll
    for (int ks = 0; ks < 4; ++ks) {           // k-steps of 16 within BK=64
      const int gl = ks * 2 + hi;              // element granule = k/8 (pre-swizzle)
      bf16x8v av[2], bv[2];
#pragma unroll
      for (int i = 0; i < 2; ++i) {
        const int ra = wr + 32 * i + l31;
        av[i] = *(const bf16x8v*)&lds_a[ra * 64 + ((gl ^ (ra & 7)) * 8)];
      }
#pragma unroll
      for (int j = 0; j < 2; ++j) {
        const int rb = wc + 32 * j + l31;
        bv[j] = *(const bf16x8v*)&lds_b[rb * 64 + ((gl ^ (rb & 7)) * 8)];
      }
#pragma unroll
      for (int i = 0; i < 2; ++i)
#pragma unroll
        for (int j = 0; j < 2; ++j)
          acc[i][j] = __builtin_amdgcn_mfma_f32_32x32x16_bf16(bv[j], av[i], acc[i][j], 0, 0, 0);
    }
  }
}

// Epilogue index helpers: with swapped operands,
//   C row (m) = m0 + wr + 32*i + l31
//   C col (n) = n0 + wc + 32*j + (reg&3) + 8*(reg>>2) + 4*hi   (reg = 4*rr+q)

// Fused K/V/R GEMM. grid 4608 blocks. XCD-chunked remap (4608 = 8*576):
// each XCD gets 32 contiguous m-tiles x all 18 n-tiles, n fastest -> A panel
// fetched once per XCD (each m-tile owned by exactly one XCD), B (3.5 MB)
// L2-resident per XCD.
__global__ __launch_bounds__(256) void gemm_kvr(
    const bf16* __restrict__ A, const bf16* __restrict__ Wcat,
    bf16* __restrict__ Kb, bf16* __restrict__ Vb, bf16* __restrict__ SRb)
{
  __shared__ __align__(16) bf16 lds_a[128 * 64];
  __shared__ __align__(16) bf16 lds_b[128 * 64];
  const int tid = threadIdx.x;
  const int bx = blockIdx.x;
  const int tl = (bx & 7) * 576 + (bx >> 3);
  const int mt = tl / 18;
  const int nt = tl - mt * 18;
  const size_t m0 = (size_t)mt * 128;
  const int n0 = nt * 128;

  f32x16v acc[2][2];
  gemm_tile_acc(A, Wcat, lds_a, lds_b, tid, m0, n0, acc);

  const int seg   = n0 / 768;
  const int ncol0 = n0 - seg * 768;
  bf16* __restrict__ dst = (seg == 0) ? Kb : (seg == 1) ? Vb : SRb;
  const int lane = tid & 63, wave = tid >> 6;
  const int l31 = lane & 31, hi = lane >> 5;
  const int wr = (wave >> 1) * 64, wc = (wave & 1) * 64;
#pragma unroll
  for (int i = 0; i < 2; ++i) {
    const size_t mrow = m0 + wr + 32 * i + l31;
#pragma unroll
    for (int j = 0; j < 2; ++j) {
      const int nb = ncol0 + wc + 32 * j + 4 * hi;
#pragma unroll
      for (int rr = 0; rr < 4; ++rr) {
        float v0 = acc[i][j][4 * rr + 0], v1 = acc[i][j][4 * rr + 1];
        float v2 = acc[i][j][4 * rr + 2], v3 = acc[i][j][4 * rr + 3];
        if (seg == 2) {
          v0 = 1.0f / (1.0f + __expf(-v0)); v1 = 1.0f / (1.0f + __expf(-v1));
          v2 = 1.0f / (1.0f + __expf(-v2)); v3 = 1.0f / (1.0f + __expf(-v3));
        }
        ushort4 pk = { bfraw(v0), bfraw(v1), bfraw(v2), bfraw(v3) };
        *(ushort4*)&dst[mrow * 768 + nb + 8 * rr] = pk;
      }
    }
  }
}

// Output GEMM: fp32 out. grid 1536 (= 8*192), same XCD-chunked remap.
__global__ __launch_bounds__(256) void gemm_out(
    const bf16* __restrict__ A, const bf16* __restrict__ W,
    float* __restrict__ out)
{
  __shared__ __align__(16) bf16 lds_a[128 * 64];
  __shared__ __align__(16) bf16 lds_b[128 * 64];
  const int tid = threadIdx.x;
  const int bx = blockIdx.x;
  const int tl = (bx & 7) * 192 + (bx >> 3);
  const int mt = tl / 6;
  const int nt = tl - mt * 6;
  const size_t m0 = (size_t)mt * 128;
  const int n0 = nt * 128;

  f32x16v acc[2][2];
  gemm_tile_acc(A, W, lds_a, lds_b, tid, m0, n0, acc);

  const int lane = tid & 63, wave = tid >> 6;
  const int l31 = lane & 31, hi = lane >> 5;
  const int wr = (wave >> 1) * 64, wc = (wave & 1) * 64;
#pragma unroll
  for (int i = 0; i < 2; ++i) {
    const size_t mrow = m0 + wr + 32 * i + l31;
#pragma unroll
    for (int j = 0; j < 2; ++j) {
      const int nb = n0 + wc + 32 * j + 4 * hi;
#pragma unroll
      for (int rr = 0; rr < 4; ++rr) {
        float4 pk = { acc[i][j][4 * rr + 0], acc[i][j][4 * rr + 1],
                      acc[i][j][4 * rr + 2], acc[i][j][4 * rr + 3] };
        *(float4*)&out[mrow * 768 + nb + 8 * rr] = pk;
      }
    }
  }
}

// ------------------------------------------------------------ WKV chunk scan
// G=128 chunks of L=32. 4 channels/thread. State math fp32.
__global__ void wkv_phaseA(const bf16* __restrict__ K, const bf16* __restrict__ V,
                           const float* __restrict__ sd,
                           float* __restrict__ sA, float* __restrict__ sB, float* __restrict__ sP)
{
  const int idx = blockIdx.x * 256 + threadIdx.x;
  const int c4 = idx % 192;
  const int bg = idx / 192;
  const int g  = bg & 127;
  const int b  = bg >> 7;
  const int c0 = c4 * 4;
  float w[4], aa[4], bb[4], pp[4];
#pragma unroll
  for (int e = 0; e < 4; ++e) {
    w[e] = sd[c0 + e] * (1.0f / 4096.0f);
    aa[e] = 0.f; bb[e] = 0.f; pp[e] = -1e38f;
  }
  const size_t base = ((size_t)b * 4096 + (size_t)g * 32) * 768 + c0;
  const uint2* Kp = (const uint2*)(K + base);
  const uint2* Vp = (const uint2*)(V + base);
#pragma unroll 4
  for (int t = 0; t < 32; ++t) {
    const uint2 ku = Kp[(size_t)t * 192];
    const uint2 vu = Vp[(size_t)t * 192];
    const float kc[4] = { bflo(ku.x), bfhi(ku.x), bflo(ku.y), bfhi(ku.y) };
    const float vc[4] = { bflo(vu.x), bfhi(vu.x), bflo(vu.y), bfhi(vu.y) };
#pragma unroll
    for (int e = 0; e < 4; ++e) {
      const float ww2 = w[e] + pp[e];
      const float p2  = fmaxf(ww2, kc[e]);
      const float e1b = __expf(ww2 - p2);
      const float e2b = __expf(kc[e] - p2);
      aa[e] = e1b * aa[e] + e2b * vc[e];
      bb[e] = e1b * bb[e] + e2b;
      pp[e] = p2;
    }
  }
  const int o = g * 6144 + b * 768 + c0;
#pragma unroll
  for (int e = 0; e < 4; ++e) { sA[o + e] = aa[e]; sB[o + e] = bb[e]; sP[o + e] = pp[e]; }
}

// 96 blocks x 64 threads (was 24x256): 4x CU coverage for this latency-bound
// serial scan; explicit next-g prefetch hides load latency under the exp chain.
__global__ void wkv_phaseB(const float* __restrict__ sA, const float* __restrict__ sB,
                           const float* __restrict__ sP,
                           float* __restrict__ iA, float* __restrict__ iB, float* __restrict__ iP,
                           const float* __restrict__ sd)
{
  const int bc = blockIdx.x * 64 + threadIdx.x;     // B*C = 6144
  const int c  = bc % 768;
  const float Lw = 32.0f * (sd[c] * (1.0f / 4096.0f));
  float aa = 0.f, bb = 0.f, pp = -1e38f;
  float la = sA[bc], lb = sB[bc], lp = sP[bc];
  for (int g = 0; g < 128; ++g) {
    const int o = g * 6144 + bc;
    float la2 = 0.f, lb2 = 0.f, lp2 = 0.f;
    if (g < 127) { la2 = sA[o + 6144]; lb2 = sB[o + 6144]; lp2 = sP[o + 6144]; }
    iA[o] = aa; iB[o] = bb; iP[o] = pp;             // state BEFORE chunk g
    const float pd = pp + Lw;
    const float pn = fmaxf(pd, lp);
    const float e0 = __expf(pd - pn);
    const float e1 = __expf(lp - pn);
    aa = e0 * aa + e1 * la;
    bb = e0 * bb + e1 * lb;
    pp = pn;
    la = la2; lb = lb2; lp = lp2;
  }
}

__global__ void wkv_phaseC(const bf16* __restrict__ K, const bf16* __restrict__ V,
                           const bf16* __restrict__ SR,
                           const float* __restrict__ iA, const float* __restrict__ iB,
                           const float* __restrict__ iP,
                           const float* __restrict__ sd, const float* __restrict__ sf,
                           bf16* __restrict__ RY)
{
  const int idx = blockIdx.x * 256 + threadIdx.x;
  const int c4 = idx % 192;
  const int bg = idx / 192;
  const int g  = bg & 127;
  const int b  = bg >> 7;
  const int c0 = c4 * 4;
  const int o = g * 6144 + b * 768 + c0;
  float w[4], u[4], aa[4], bb[4], pp[4];
#pragma unroll
  for (int e = 0; e < 4; ++e) {
    w[e] = sd[c0 + e] * (1.0f / 4096.0f);
    u[e] = sf[c0 + e] * (1.0f / 4096.0f);
    aa[e] = iA[o + e]; bb[e] = iB[o + e]; pp[e] = iP[o + e];
  }
  const size_t base = ((size_t)b * 4096 + (size_t)g * 32) * 768 + c0;
  const uint2* Kp = (const uint2*)(K + base);
  const uint2* Vp = (const uint2*)(V + base);
  const uint2* Sp = (const uint2*)(SR + base);
  uint2* Rp = (uint2*)(RY + base);
#pragma unroll 4
  for (int t = 0; t < 32; ++t) {
    const uint2 ku = Kp[(size_t)t * 192];
    const uint2 vu = Vp[(size_t)t * 192];
    const uint2 su = Sp[(size_t)t * 192];
    const float kc[4] = { bflo(ku.x), bfhi(ku.x), bflo(ku.y), bfhi(ku.y) };
    const float vc[4] = { bflo(vu.x), bfhi(vu.x), bflo(vu.y), bfhi(vu.y) };
    const float sc[4] = { bflo(su.x), bfhi(su.x), bflo(su.y), bfhi(su.y) };
    float y[4];
#pragma unroll
    for (int e = 0; e < 4; ++e) {
      const float ww = u[e] + kc[e];
      const float p  = fmaxf(pp[e], ww);
      const float e1 = __expf(pp[e] - p);
      const float e2 = __expf(ww - p);
      y[e] = (e1 * aa[e] + e2 * vc[e]) / (e1 * bb[e] + e2) * sc[e];
      const float ww2 = w[e] + pp[e];
      const float p2  = fmaxf(ww2, kc[e]);
      const float e1b = __expf(ww2 - p2);
      const float e2b = __expf(kc[e] - p2);
      aa[e] = e1b * aa[e] + e2b * vc[e];
      bb[e] = e1b * bb[e] + e2b;
      pp[e] = p2;
    }
    uint2 r; r.x = packbf(y[0], y[1]); r.y = packbf(y[2], y[3]);
    Rp[(size_t)t * 192] = r;
  }
}

// ---------------------------------------------------------------------------
extern "C" void kernel_launch(void* const* d_in, const int* in_sizes, int n_in,
                              void* d_out, int out_size, void* d_ws, size_t ws_size,
                              hipStream_t stream)
{
  const float* x  = (const float*)d_in[0];
  const float* wk = (const float*)d_in[1];
  const float* wv = (const float*)d_in[2];
  const float* wr = (const float*)d_in[3];
  const float* wo = (const float*)d_in[4];
  const float* sd = (const float*)d_in[5];
  const float* sf = (const float*)d_in[6];
  float* out = (float*)d_out;

  char* ws = (char*)d_ws;
  bf16*  x_bf  = (bf16*) (ws + 0);            // 25165824 * 2
  bf16*  wcat  = (bf16*) (ws + 50331648);     // 2304x768 bf16
  bf16*  wo_bf = (bf16*) (ws + 53870592);
  bf16*  Kb    = (bf16*) (ws + 55050240);     // 25165824 * 2 each
  bf16*  Vb    = (bf16*) (ws + 105381888);
  bf16*  SRb   = (bf16*) (ws + 155713536);
  float* sumA  = (float*)(ws + 206045184);    // 128*6144 floats (3 MB) each
  float* sumB  = (float*)(ws + 209190912);
  float* sumP  = (float*)(ws + 212336640);
  float* iniA  = (float*)(ws + 215482368);
  float* iniB  = (float*)(ws + 218628096);
  float* iniP  = (float*)(ws + 221773824);
  bf16*  ry_bf = x_bf;                        // x dead after gemm_kvr -> alias

  f2b4_all<<<26880, 256, 0, stream>>>(x, wk, wv, wr, wo, x_bf, wcat, wo_bf);

  gemm_kvr<<<4608, 256, 0, stream>>>(x_bf, wcat, Kb, Vb, SRb);

  wkv_phaseA<<<768, 256, 0, stream>>>(Kb, Vb, sd, sumA, sumB, sumP);
  wkv_phaseB<<<96,  64, 0, stream>>>(sumA, sumB, sumP, iniA, iniB, iniP, sd);
  wkv_phaseC<<<768, 256, 0, stream>>>(Kb, Vb, SRb, iniA, iniB, iniP, sd, sf, ry_bf);

  gemm_out<<<1536, 256, 0, stream>>>(ry_bf, wo_bf, out);
}

// Round 3
// 475.410 us; speedup vs baseline: 1.0090x; 1.0090x over previous
//
#include <hip/hip_runtime.h>
#include <hip/hip_bf16.h>

using bf16 = __hip_bfloat16;
typedef short bf16x8v  __attribute__((ext_vector_type(8)));
typedef float f32x16v  __attribute__((ext_vector_type(16)));

#define GLD_LDS16(g, l) __builtin_amdgcn_global_load_lds(                      \
    (const __attribute__((address_space(1))) void*)(g),                        \
    (__attribute__((address_space(3))) void*)(l), 16, 0, 0)

__device__ __forceinline__ float bflo(unsigned int u) {
  union { unsigned int i; float f; } c; c.i = u << 16; return c.f;
}
__device__ __forceinline__ float bfhi(unsigned int u) {
  union { unsigned int i; float f; } c; c.i = u & 0xffff0000u; return c.f;
}
__device__ __forceinline__ unsigned int packbf(float a, float b) {
  return (unsigned int)(__hip_bfloat16_raw(__float2bfloat16(a)).x) |
         ((unsigned int)(__hip_bfloat16_raw(__float2bfloat16(b)).x) << 16);
}
__device__ __forceinline__ unsigned short bfraw(float a) {
  return __hip_bfloat16_raw(__float2bfloat16(a)).x;
}

// ------------------------------------------------- all fp32->bf16 casts, one launch
__global__ void f2b4_all(const float* __restrict__ x,  const float* __restrict__ wk,
                         const float* __restrict__ wv, const float* __restrict__ wr,
                         const float* __restrict__ wo,
                         bf16* __restrict__ x_bf, bf16* __restrict__ wcat,
                         bf16* __restrict__ wo_bf) {
  int i = blockIdx.x * blockDim.x + threadIdx.x;
  const float* s; bf16* d; int idx;
  if (i < 6291456) { s = x; d = x_bf; idx = i; }
  else {
    int j = i - 6291456;
    int seg = j / 147456;
    idx = j - seg * 147456;
    if (seg == 0)      { s = wk; d = wcat; }
    else if (seg == 1) { s = wv; d = wcat + 589824; }
    else if (seg == 2) { s = wr; d = wcat + 1179648; }
    else               { s = wo; d = wo_bf; }
  }
  const float4 f = reinterpret_cast<const float4*>(s)[idx];
  struct B4 { bf16 a, b, c, d; };
  B4 o = { __float2bfloat16(f.x), __float2bfloat16(f.y),
           __float2bfloat16(f.z), __float2bfloat16(f.w) };
  reinterpret_cast<B4*>(d)[idx] = o;
}

// --------------------------------------------------------------- GEMM core
// R3: block tile 256x128, 4 waves, WAVE TILE 128x64 (was 64x64).
// Rationale (R2 post-mortem): kernel is LDS-read-BW-bound, not barrier-bound.
// Old: 4 reads feed 4 MFMA (1024 B/MFMA), LDS:MFMA cycle ratio ~4:1 -> 33%
// MfmaUtil ceiling (measured 33%). New: 6 reads feed 8 MFMA (768 B/MFMA),
// ratio ~1.5:1 -> ~66% ceiling. Everything else verbatim from the proven
// round-0 kernel: BK=64, granule-XOR swizzle, global_load_lds w=16,
// swapped-operand v_mfma_f32_32x32x16_bf16, 2-barrier K-loop.
// Grid order: round-0 L3-chunked (chunk x nt x mm, mm fastest) - the R2
// XCD remap RAISED fetch 112->160MB; L3 chunk-blocking is what works here.
__device__ __forceinline__ void gemm_tile_acc(
    const bf16* __restrict__ A, const bf16* __restrict__ W,
    bf16* lds_a, bf16* lds_b, int tid, size_t m0, int n0, f32x16v acc[4][2])
{
  const int lane = tid & 63;
  const int wave = tid >> 6;
  const int l31  = lane & 31;
  const int hi   = lane >> 5;
  const int wr   = (wave >> 1) * 128;   // wave row base (2 wave-rows of 128)
  const int wc   = (wave & 1) * 64;     // wave col base (2 wave-cols of 64)

  int srow[8], scol[8];
#pragma unroll
  for (int q = 0; q < 8; ++q) {
    const int s = tid + q * 256;
    srow[q] = s >> 3;                    // 0..255
    scol[q] = (((s & 7) ^ (srow[q] & 7)) * 8);
  }

#pragma unroll
  for (int i = 0; i < 4; ++i)
#pragma unroll
    for (int j = 0; j < 2; ++j)
#pragma unroll
      for (int r = 0; r < 16; ++r) acc[i][j][r] = 0.0f;

  for (int k0 = 0; k0 < 768; k0 += 64) {
    __syncthreads();
#pragma unroll
    for (int q = 0; q < 8; ++q)          // A: 256 rows x 64 k
      GLD_LDS16(A + (m0 + srow[q]) * 768 + k0 + scol[q], &lds_a[(size_t)(tid + q * 256) * 8]);
#pragma unroll
    for (int q = 0; q < 4; ++q)          // B: 128 rows x 64 k
      GLD_LDS16(W + (size_t)(n0 + srow[q]) * 768 + k0 + scol[q], &lds_b[(size_t)(tid + q * 256) * 8]);
    __syncthreads();

#pragma unroll
    for (int ks = 0; ks < 4; ++ks) {           // k-steps of 16 within BK=64
      const int gl = ks * 2 + hi;              // element granule = k/8 (pre-swizzle)
      bf16x8v av[4], bv[2];
#pragma unroll
      for (int i = 0; i < 4; ++i) {
        const int ra = wr + 32 * i + l31;
        av[i] = *(const bf16x8v*)&lds_a[ra * 64 + ((gl ^ (ra & 7)) * 8)];
      }
#pragma unroll
      for (int j = 0; j < 2; ++j) {
        const int rb = wc + 32 * j + l31;
        bv[j] = *(const bf16x8v*)&lds_b[rb * 64 + ((gl ^ (rb & 7)) * 8)];
      }
#pragma unroll
      for (int i = 0; i < 4; ++i)
#pragma unroll
        for (int j = 0; j < 2; ++j)
          acc[i][j] = __builtin_amdgcn_mfma_f32_32x32x16_bf16(bv[j], av[i], acc[i][j], 0, 0, 0);
    }
  }
}

// Epilogue index helpers: with swapped operands,
//   C row (m) = m0 + wr + 32*i + l31                     (i = 0..3)
//   C col (n) = n0 + wc + 32*j + (reg&3) + 8*(reg>>2) + 4*hi   (reg = 4*rr+q)

// Fused K/V/R GEMM. M-tiles 128 (BM=256), n-tiles 18. grid 2304 =
// chunk(4) x nt(18) x mm(32), mm fastest (L3 keeps 12.5MB A-chunk resident
// across the 18 n-passes).
__global__ __launch_bounds__(256, 2) void gemm_kvr(
    const bf16* __restrict__ A, const bf16* __restrict__ Wcat,
    bf16* __restrict__ Kb, bf16* __restrict__ Vb, bf16* __restrict__ SRb)
{
  __shared__ __align__(16) bf16 lds_a[256 * 64];
  __shared__ __align__(16) bf16 lds_b[128 * 64];
  const int tid = threadIdx.x;
  const int bx = blockIdx.x;
  const int chunk = bx / 576;
  const int rem   = bx % 576;
  const int nt    = rem >> 5;
  const int mm    = rem & 31;
  const size_t m0 = (size_t)(chunk * 32 + mm) * 256;
  const int n0 = nt * 128;

  f32x16v acc[4][2];
  gemm_tile_acc(A, Wcat, lds_a, lds_b, tid, m0, n0, acc);

  const int seg   = n0 / 768;
  const int ncol0 = n0 - seg * 768;
  bf16* __restrict__ dst = (seg == 0) ? Kb : (seg == 1) ? Vb : SRb;
  const int lane = tid & 63, wave = tid >> 6;
  const int l31 = lane & 31, hi = lane >> 5;
  const int wr = (wave >> 1) * 128, wc = (wave & 1) * 64;
#pragma unroll
  for (int i = 0; i < 4; ++i) {
    const size_t mrow = m0 + wr + 32 * i + l31;
#pragma unroll
    for (int j = 0; j < 2; ++j) {
      const int nb = ncol0 + wc + 32 * j + 4 * hi;
#pragma unroll
      for (int rr = 0; rr < 4; ++rr) {
        float v0 = acc[i][j][4 * rr + 0], v1 = acc[i][j][4 * rr + 1];
        float v2 = acc[i][j][4 * rr + 2], v3 = acc[i][j][4 * rr + 3];
        if (seg == 2) {
          v0 = 1.0f / (1.0f + __expf(-v0)); v1 = 1.0f / (1.0f + __expf(-v1));
          v2 = 1.0f / (1.0f + __expf(-v2)); v3 = 1.0f / (1.0f + __expf(-v3));
        }
        ushort4 pk = { bfraw(v0), bfraw(v1), bfraw(v2), bfraw(v3) };
        *(ushort4*)&dst[mrow * 768 + nb + 8 * rr] = pk;
      }
    }
  }
}

// Output GEMM: fp32 out. M-tiles 128, n-tiles 6. grid 768 =
// chunk(4) x nt(6) x mm(32), mm fastest.
__global__ __launch_bounds__(256, 2) void gemm_out(
    const bf16* __restrict__ A, const bf16* __restrict__ W,
    float* __restrict__ out)
{
  __shared__ __align__(16) bf16 lds_a[256 * 64];
  __shared__ __align__(16) bf16 lds_b[128 * 64];
  const int tid = threadIdx.x;
  const int bx = blockIdx.x;
  const int chunk = bx / 192;
  const int rem   = bx % 192;
  const int nt    = rem >> 5;
  const int mm    = rem & 31;
  const size_t m0 = (size_t)(chunk * 32 + mm) * 256;
  const int n0 = nt * 128;

  f32x16v acc[4][2];
  gemm_tile_acc(A, W, lds_a, lds_b, tid, m0, n0, acc);

  const int lane = tid & 63, wave = tid >> 6;
  const int l31 = lane & 31, hi = lane >> 5;
  const int wr = (wave >> 1) * 128, wc = (wave & 1) * 64;
#pragma unroll
  for (int i = 0; i < 4; ++i) {
    const size_t mrow = m0 + wr + 32 * i + l31;
#pragma unroll
    for (int j = 0; j < 2; ++j) {
      const int nb = n0 + wc + 32 * j + 4 * hi;
#pragma unroll
      for (int rr = 0; rr < 4; ++rr) {
        float4 pk = { acc[i][j][4 * rr + 0], acc[i][j][4 * rr + 1],
                      acc[i][j][4 * rr + 2], acc[i][j][4 * rr + 3] };
        *(float4*)&out[mrow * 768 + nb + 8 * rr] = pk;
      }
    }
  }
}

// ------------------------------------------------------------ WKV chunk scan
// G=128 chunks of L=32. 4 channels/thread. State math fp32.
__global__ void wkv_phaseA(const bf16* __restrict__ K, const bf16* __restrict__ V,
                           const float* __restrict__ sd,
                           float* __restrict__ sA, float* __restrict__ sB, float* __restrict__ sP)
{
  const int idx = blockIdx.x * 256 + threadIdx.x;
  const int c4 = idx % 192;
  const int bg = idx / 192;
  const int g  = bg & 127;
  const int b  = bg >> 7;
  const int c0 = c4 * 4;
  float w[4], aa[4], bb[4], pp[4];
#pragma unroll
  for (int e = 0; e < 4; ++e) {
    w[e] = sd[c0 + e] * (1.0f / 4096.0f);
    aa[e] = 0.f; bb[e] = 0.f; pp[e] = -1e38f;
  }
  const size_t base = ((size_t)b * 4096 + (size_t)g * 32) * 768 + c0;
  const uint2* Kp = (const uint2*)(K + base);
  const uint2* Vp = (const uint2*)(V + base);
#pragma unroll 4
  for (int t = 0; t < 32; ++t) {
    const uint2 ku = Kp[(size_t)t * 192];
    const uint2 vu = Vp[(size_t)t * 192];
    const float kc[4] = { bflo(ku.x), bfhi(ku.x), bflo(ku.y), bfhi(ku.y) };
    const float vc[4] = { bflo(vu.x), bfhi(vu.x), bflo(vu.y), bfhi(vu.y) };
#pragma unroll
    for (int e = 0; e < 4; ++e) {
      const float ww2 = w[e] + pp[e];
      const float p2  = fmaxf(ww2, kc[e]);
      const float e1b = __expf(ww2 - p2);
      const float e2b = __expf(kc[e] - p2);
      aa[e] = e1b * aa[e] + e2b * vc[e];
      bb[e] = e1b * bb[e] + e2b;
      pp[e] = p2;
    }
  }
  const int o = g * 6144 + b * 768 + c0;
#pragma unroll
  for (int e = 0; e < 4; ++e) { sA[o + e] = aa[e]; sB[o + e] = bb[e]; sP[o + e] = pp[e]; }
}

// 96 blocks x 64 threads: 4x CU coverage for this latency-bound serial scan;
// explicit next-g prefetch hides load latency under the exp chain.
__global__ void wkv_phaseB(const float* __restrict__ sA, const float* __restrict__ sB,
                           const float* __restrict__ sP,
                           float* __restrict__ iA, float* __restrict__ iB, float* __restrict__ iP,
                           const float* __restrict__ sd)
{
  const int bc = blockIdx.x * 64 + threadIdx.x;     // B*C = 6144
  const int c  = bc % 768;
  const float Lw = 32.0f * (sd[c] * (1.0f / 4096.0f));
  float aa = 0.f, bb = 0.f, pp = -1e38f;
  float la = sA[bc], lb = sB[bc], lp = sP[bc];
  for (int g = 0; g < 128; ++g) {
    const int o = g * 6144 + bc;
    float la2 = 0.f, lb2 = 0.f, lp2 = 0.f;
    if (g < 127) { la2 = sA[o + 6144]; lb2 = sB[o + 6144]; lp2 = sP[o + 6144]; }
    iA[o] = aa; iB[o] = bb; iP[o] = pp;             // state BEFORE chunk g
    const float pd = pp + Lw;
    const float pn = fmaxf(pd, lp);
    const float e0 = __expf(pd - pn);
    const float e1 = __expf(lp - pn);
    aa = e0 * aa + e1 * la;
    bb = e0 * bb + e1 * lb;
    pp = pn;
    la = la2; lb = lb2; lp = lp2;
  }
}

__global__ void wkv_phaseC(const bf16* __restrict__ K, const bf16* __restrict__ V,
                           const bf16* __restrict__ SR,
                           const float* __restrict__ iA, const float* __restrict__ iB,
                           const float* __restrict__ iP,
                           const float* __restrict__ sd, const float* __restrict__ sf,
                           bf16* __restrict__ RY)
{
  const int idx = blockIdx.x * 256 + threadIdx.x;
  const int c4 = idx % 192;
  const int bg = idx / 192;
  const int g  = bg & 127;
  const int b  = bg >> 7;
  const int c0 = c4 * 4;
  const int o = g * 6144 + b * 768 + c0;
  float w[4], u[4], aa[4], bb[4], pp[4];
#pragma unroll
  for (int e = 0; e < 4; ++e) {
    w[e] = sd[c0 + e] * (1.0f / 4096.0f);
    u[e] = sf[c0 + e] * (1.0f / 4096.0f);
    aa[e] = iA[o + e]; bb[e] = iB[o + e]; pp[e] = iP[o + e];
  }
  const size_t base = ((size_t)b * 4096 + (size_t)g * 32) * 768 + c0;
  const uint2* Kp = (const uint2*)(K + base);
  const uint2* Vp = (const uint2*)(V + base);
  const uint2* Sp = (const uint2*)(SR + base);
  uint2* Rp = (uint2*)(RY + base);
#pragma unroll 4
  for (int t = 0; t < 32; ++t) {
    const uint2 ku = Kp[(size_t)t * 192];
    const uint2 vu = Vp[(size_t)t * 192];
    const uint2 su = Sp[(size_t)t * 192];
    const float kc[4] = { bflo(ku.x), bfhi(ku.x), bflo(ku.y), bfhi(ku.y) };
    const float vc[4] = { bflo(vu.x), bfhi(vu.x), bflo(vu.y), bfhi(vu.y) };
    const float sc[4] = { bflo(su.x), bfhi(su.x), bflo(su.y), bfhi(su.y) };
    float y[4];
#pragma unroll
    for (int e = 0; e < 4; ++e) {
      const float ww = u[e] + kc[e];
      const float p  = fmaxf(pp[e], ww);
      const float e1 = __expf(pp[e] - p);
      const float e2 = __expf(ww - p);
      y[e] = (e1 * aa[e] + e2 * vc[e]) / (e1 * bb[e] + e2) * sc[e];
      const float ww2 = w[e] + pp[e];
      const float p2  = fmaxf(ww2, kc[e]);
      const float e1b = __expf(ww2 - p2);
      const float e2b = __expf(kc[e] - p2);
      aa[e] = e1b * aa[e] + e2b * vc[e];
      bb[e] = e1b * bb[e] + e2b;
      pp[e] = p2;
    }
    uint2 r; r.x = packbf(y[0], y[1]); r.y = packbf(y[2], y[3]);
    Rp[(size_t)t * 192] = r;
  }
}

// ---------------------------------------------------------------------------
extern "C" void kernel_launch(void* const* d_in, const int* in_sizes, int n_in,
                              void* d_out, int out_size, void* d_ws, size_t ws_size,
                              hipStream_t stream)
{
  const float* x  = (const float*)d_in[0];
  const float* wk = (const float*)d_in[1];
  const float* wv = (const float*)d_in[2];
  const float* wr = (const float*)d_in[3];
  const float* wo = (const float*)d_in[4];
  const float* sd = (const float*)d_in[5];
  const float* sf = (const float*)d_in[6];
  float* out = (float*)d_out;

  char* ws = (char*)d_ws;
  bf16*  x_bf  = (bf16*) (ws + 0);            // 25165824 * 2
  bf16*  wcat  = (bf16*) (ws + 50331648);     // 2304x768 bf16
  bf16*  wo_bf = (bf16*) (ws + 53870592);
  bf16*  Kb    = (bf16*) (ws + 55050240);     // 25165824 * 2 each
  bf16*  Vb    = (bf16*) (ws + 105381888);
  bf16*  SRb   = (bf16*) (ws + 155713536);
  float* sumA  = (float*)(ws + 206045184);    // 128*6144 floats (3 MB) each
  float* sumB  = (float*)(ws + 209190912);
  float* sumP  = (float*)(ws + 212336640);
  float* iniA  = (float*)(ws + 215482368);
  float* iniB  = (float*)(ws + 218628096);
  float* iniP  = (float*)(ws + 221773824);
  bf16*  ry_bf = x_bf;                        // x dead after gemm_kvr -> alias

  f2b4_all<<<26880, 256, 0, stream>>>(x, wk, wv, wr, wo, x_bf, wcat, wo_bf);

  gemm_kvr<<<2304, 256, 0, stream>>>(x_bf, wcat, Kb, Vb, SRb);

  wkv_phaseA<<<768, 256, 0, stream>>>(Kb, Vb, sd, sumA, sumB, sumP);
  wkv_phaseB<<<96,  64, 0, stream>>>(sumA, sumB, sumP, iniA, iniB, iniP, sd);
  wkv_phaseC<<<768, 256, 0, stream>>>(Kb, Vb, SRb, iniA, iniB, iniP, sd, sf, ry_bf);

  gemm_out<<<768, 256, 0, stream>>>(ry_bf, wo_bf, out);
}